// Round 1
// baseline (423.273 us; speedup 1.0000x reference)
//
#include <hip/hip_runtime.h>

typedef short short8 __attribute__((ext_vector_type(8)));
typedef float f32x4 __attribute__((ext_vector_type(4)));

// fp32 -> bf16 (round-to-nearest-even), two at a time packed into a u32
__device__ inline unsigned bfpack(float a, float b) {
    union { float f; unsigned u; } ua, ub;
    ua.f = a; ub.f = b;
    unsigned lo = (ua.u + 0x7FFFu + ((ua.u >> 16) & 1u)) >> 16;
    unsigned hi = (ub.u + 0x7FFFu + ((ub.u >> 16) & 1u)) & 0xFFFF0000u;
    return lo | hi;
}

// swizzled byte offset inside a [128 rows][32 bf16] LDS tile (row stride 64B,
// four 16B k-group slots per row; XOR with row bits spreads banks)
__device__ inline int swz(int row, int kgrp) {
    return row * 64 + ((kgrp ^ ((row >> 1) & 3)) << 4);
}

// One GEMM ( [B*K_L x 512] @ [512 x N] ) + closed-form scatter epilogue.
// MODE 0/1/2 = CNN layer. Stream order gives the cross-kernel += dependency.
template <int MODE>
__global__ __launch_bounds__(256)
void gemm_scatter(const float* __restrict__ X, const float* __restrict__ W,
                  const float* __restrict__ BIAS, float* __restrict__ Y)
{
    constexpr int K_L  = (MODE == 0) ? 64 : (MODE == 1) ? 128 : 256;
    constexpr int LOGK = (MODE == 0) ? 6  : (MODE == 1) ? 7   : 8;
    constexpr int N    = (MODE == 0) ? 1180 : (MODE == 1) ? 2881 : 1153;
    constexpr int XOFF = (MODE == 0) ? 0 : (MODE == 1) ? 64 : 192;
    constexpr int NT   = (N + 127) / 128;

    __shared__ __align__(16) unsigned short lA[128 * 32];
    __shared__ __align__(16) unsigned short lB[128 * 32];

    const int t    = threadIdx.x;
    const int lane = t & 63;
    const int wave = t >> 6;
    const int wr   = wave >> 1, wc = wave & 1;
    const int nt   = blockIdx.x % NT;
    const int mt   = blockIdx.x / NT;
    const int m0   = mt * 128;
    const int n0   = nt * 128;

    f32x4 acc[4][4] = {};

    for (int kk = 0; kk < 512; kk += 32) {
        // ---- stage A: x tile [128 rows][32 k] fp32 -> bf16 LDS (swizzled)
        #pragma unroll
        for (int i = 0; i < 4; ++i) {
            int c   = t + i * 256;        // 1024 float4-chunks
            int row = c >> 3;             // 0..127
            int k4  = (c & 7) << 2;       // 0,4,...,28
            int m   = m0 + row;
            int b   = m >> LOGK;
            int kd  = m & (K_L - 1);
            const float4 v = *(const float4*)(X + ((size_t)(b * 448 + XOFF + kd) << 9) + kk + k4);
            uint2 u;
            u.x = bfpack(v.x, v.y);
            u.y = bfpack(v.z, v.w);
            *(uint2*)((char*)lA + swz(row, k4 >> 3) + ((k4 & 4) << 1)) = u;
        }
        // ---- stage B: W tile transposed to [128 n][32 k] bf16 LDS (swizzled)
        // per-lane: 8 k-strided loads (each coalesced across lanes in n)
        #pragma unroll
        for (int i = 0; i < 2; ++i) {
            int tau = t + i * 256;        // 512 tasks: 128 n x 4 kgroups
            int kg  = tau >> 7;           // 0..3
            int n   = tau & 127;
            int gc  = n0 + n; if (gc > N - 1) gc = N - 1;   // clamp N-tail
            const float* p = W + (size_t)(kk + kg * 8) * N + gc;
            float w0 = p[0],            w1 = p[(size_t)N],     w2 = p[2 * (size_t)N],
                  w3 = p[3 * (size_t)N], w4 = p[4 * (size_t)N], w5 = p[5 * (size_t)N],
                  w6 = p[6 * (size_t)N], w7 = p[7 * (size_t)N];
            uint4 u;
            u.x = bfpack(w0, w1); u.y = bfpack(w2, w3);
            u.z = bfpack(w4, w5); u.w = bfpack(w6, w7);
            *(uint4*)((char*)lB + swz(n, kg)) = u;
        }
        __syncthreads();

        const int kgl = lane >> 4;
        const int lr16 = lane & 15;
        short8 af[4], bfr[4];
        #pragma unroll
        for (int mi = 0; mi < 4; ++mi)
            af[mi] = *(const short8*)((const char*)lA + swz(wr * 64 + mi * 16 + lr16, kgl));
        #pragma unroll
        for (int ni = 0; ni < 4; ++ni)
            bfr[ni] = *(const short8*)((const char*)lB + swz(wc * 64 + ni * 16 + lr16, kgl));
        #pragma unroll
        for (int mi = 0; mi < 4; ++mi)
            #pragma unroll
            for (int ni = 0; ni < 4; ++ni)
                acc[mi][ni] = __builtin_amdgcn_mfma_f32_16x16x32_bf16(
                    af[mi], bfr[ni], acc[mi][ni], 0, 0, 0);
        __syncthreads();
    }

    // ---- epilogue: bias add + closed-form scatter
    const int lr = lane & 15;   // = output col within 16x16 frag
    const int lq = lane >> 4;   // row group
    #pragma unroll
    for (int ni = 0; ni < 4; ++ni) {
        const int n = n0 + wc * 64 + ni * 16 + lr;
        if (n >= N) continue;
        const float bias = BIAS[n];
        #pragma unroll
        for (int mi = 0; mi < 4; ++mi) {
            #pragma unroll
            for (int r = 0; r < 4; ++r) {
                const int m  = m0 + wr * 64 + mi * 16 + lq * 4 + r;
                const int b  = m >> LOGK;
                const int kd = m & (K_L - 1);
                const float v = acc[mi][ni][r] + bias;
                float* yb = Y + (size_t)b * 370816;
                if (MODE == 0) {
                    if (n < 27)       yb[kd * 27 + n] = v;          // own weights
                    else if (n == 27) yb[1728 + kd]   = v;          // own bias
                    else {                                          // ext into L1 region
                        int tt = n - 28, kn = tt / 9, j = tt - kn * 9;
                        yb[1792 + kn * 576 + kd * 9 + j] = 0.5f * v;
                    }
                } else if (MODE == 1) {
                    if (n < 576)       yb[1792 + kd * 576 + n] += 0.5f * v;  // own (after L0 ext)
                    else if (n == 576) yb[75520 + kd] = 0.5f * v;            // own bias (halved)
                    else {                                                   // ext into L2 region
                        int tt = n - 577, kn = tt / 9, j = tt - kn * 9;
                        yb[75648 + kn * 1152 + kd * 9 + j] = v;
                    }
                } else {
                    if (n < 1152) yb[75648 + kd * 1152 + n] += v;   // own (after L1 ext)
                    else          yb[370560 + kd] = v;              // own bias
                }
            }
        }
    }
}

extern "C" void kernel_launch(void* const* d_in, const int* in_sizes, int n_in,
                              void* d_out, int out_size, void* d_ws, size_t ws_size,
                              hipStream_t stream)
{
    const float* x  = (const float*)d_in[0];
    const float* W0 = (const float*)d_in[1];
    const float* b0 = (const float*)d_in[2];
    const float* W1 = (const float*)d_in[3];
    const float* b1 = (const float*)d_in[4];
    const float* W2 = (const float*)d_in[5];
    const float* b2 = (const float*)d_in[6];
    float* y = (float*)d_out;

    // grids: (M/128) * ceil(N/128); order: L0 -> L1 -> L2 (stream-ordered +=)
    gemm_scatter<0><<<dim3(64 * 10),  256, 0, stream>>>(x, W0, b0, y);
    gemm_scatter<1><<<dim3(128 * 23), 256, 0, stream>>>(x, W1, b1, y);
    gemm_scatter<2><<<dim3(256 * 10), 256, 0, stream>>>(x, W2, b2, y);
}

// Round 2
// 310.154 us; speedup vs baseline: 1.3647x; 1.3647x over previous
//
#include <hip/hip_runtime.h>
#include <cstdint>

typedef short short8 __attribute__((ext_vector_type(8)));
typedef float f32x4 __attribute__((ext_vector_type(4)));

#define LDS_AS3(p) ((__attribute__((address_space(3))) unsigned*)(p))
#define GLB_AS1(p) ((const __attribute__((address_space(1))) unsigned*)(p))

// fp32 -> bf16 (round-to-nearest-even), two at a time packed into a u32
__device__ inline unsigned bfpack(float a, float b) {
    union { float f; unsigned u; } ua, ub;
    ua.f = a; ub.f = b;
    unsigned lo = (ua.u + 0x7FFFu + ((ua.u >> 16) & 1u)) >> 16;
    unsigned hi = (ub.u + 0x7FFFu + ((ub.u >> 16) & 1u)) & 0xFFFF0000u;
    return lo | hi;
}

// ---------------- prepass: convert X to bf16 (same [.,448,512] layout) ------
__global__ __launch_bounds__(256)
void cvt_x(const float* __restrict__ X, unsigned short* __restrict__ XB)
{
    const int g = blockIdx.x * 256 + threadIdx.x;   // 8 elems per thread, exact
    const float4 v0 = *(const float4*)(X + (size_t)g * 8);
    const float4 v1 = *(const float4*)(X + (size_t)g * 8 + 4);
    uint4 u;
    u.x = bfpack(v0.x, v0.y); u.y = bfpack(v0.z, v0.w);
    u.z = bfpack(v1.x, v1.y); u.w = bfpack(v1.z, v1.w);
    *(uint4*)(XB + (size_t)g * 8) = u;
}

// ------------- prepass: convert + transpose W[512][N] -> WT[N][512] bf16 ----
template <int N>
__global__ __launch_bounds__(256)
void cvt_w(const float* __restrict__ W, unsigned short* __restrict__ WT)
{
    const int g = blockIdx.x * 256 + threadIdx.x;
    if (g >= N * 64) return;
    const int n = g % N, d8 = g / N;           // lanes: consecutive n -> coalesced reads
    const float* p = W + (size_t)d8 * 8 * N + n;
    uint4 u;
    u.x = bfpack(p[0],             p[(size_t)N]);
    u.y = bfpack(p[2 * (size_t)N], p[3 * (size_t)N]);
    u.z = bfpack(p[4 * (size_t)N], p[5 * (size_t)N]);
    u.w = bfpack(p[6 * (size_t)N], p[7 * (size_t)N]);
    *(uint4*)(WT + (size_t)n * 512 + d8 * 8) = u;
}

// swizzled chunk index inside a [128 rows][4 x 16B] LDS tile
__device__ inline int swzc(int row, int kg) { return row * 4 + (kg ^ ((row >> 1) & 3)); }

// ---------------- GEMM ( [B*K_L x 512] @ [512 x N] ) + closed-form scatter --
// PRE=true : bf16 inputs from ws, global_load_lds staging (pre-swizzled source)
// PRE=false: fp32 inputs, reg-staged cvt path (fallback when ws too small)
template <int MODE, bool PRE>
__global__ __launch_bounds__(256)
void gemm_scatter(const float* __restrict__ X, const float* __restrict__ W,
                  const unsigned short* __restrict__ XB,
                  const unsigned short* __restrict__ WT,
                  const float* __restrict__ BIAS, float* __restrict__ Y)
{
    constexpr int K_L  = (MODE == 0) ? 64 : (MODE == 1) ? 128 : 256;
    constexpr int LOGK = (MODE == 0) ? 6  : (MODE == 1) ? 7   : 8;
    constexpr int N    = (MODE == 0) ? 1180 : (MODE == 1) ? 2881 : 1153;
    constexpr int XOFF = (MODE == 0) ? 0 : (MODE == 1) ? 64 : 192;
    constexpr int NT   = (N + 127) / 128;

    __shared__ __align__(16) unsigned short lA[128 * 32];
    __shared__ __align__(16) unsigned short lB[128 * 32];

    const int t    = threadIdx.x;
    const int lane = t & 63;
    const int wave = t >> 6;
    const int wr   = wave >> 1, wc = wave & 1;
    const int nt   = blockIdx.x % NT;
    const int mt   = blockIdx.x / NT;
    const int m0   = mt * 128;
    const int n0   = nt * 128;

    f32x4 acc[4][4] = {};

    for (int kk = 0; kk < 512; kk += 32) {
        if constexpr (PRE) {
            // ---- stage A: 8KB bf16, 512x16B chunks, linear LDS dest,
            //      bank-swizzle applied on the GLOBAL source side (rule #21)
            #pragma unroll
            for (int i = 0; i < 2; ++i) {
                const int cidx = i * 256 + t;
                const int row  = cidx >> 2;
                const int kgl  = (cidx & 3) ^ ((row >> 1) & 3);
                const int m    = m0 + row;
                const int b    = m >> LOGK;
                const int kd   = m & (K_L - 1);
                const unsigned short* gp =
                    XB + ((size_t)(b * 448 + XOFF + kd) << 9) + kk + kgl * 8;
                __builtin_amdgcn_global_load_lds(GLB_AS1(gp), LDS_AS3(lA + cidx * 8), 16, 0, 0);
            }
            // ---- stage B from transposed bf16 W
            #pragma unroll
            for (int i = 0; i < 2; ++i) {
                const int cidx = i * 256 + t;
                const int row  = cidx >> 2;
                const int kgl  = (cidx & 3) ^ ((row >> 1) & 3);
                int gc = n0 + row; if (gc > N - 1) gc = N - 1;   // N-tail clamp
                const unsigned short* gp = WT + (size_t)gc * 512 + kk + kgl * 8;
                __builtin_amdgcn_global_load_lds(GLB_AS1(gp), LDS_AS3(lB + cidx * 8), 16, 0, 0);
            }
        } else {
            // ---- fallback: fp32 loads + in-loop cvt (R0 path)
            #pragma unroll
            for (int i = 0; i < 4; ++i) {
                int c = t + i * 256, row = c >> 3, k4 = (c & 7) << 2;
                int m = m0 + row, b = m >> LOGK, kd = m & (K_L - 1);
                const float4 v = *(const float4*)(X + ((size_t)(b * 448 + XOFF + kd) << 9) + kk + k4);
                uint2 u; u.x = bfpack(v.x, v.y); u.y = bfpack(v.z, v.w);
                *(uint2*)((char*)lA + swzc(row, k4 >> 3) * 16 + ((k4 & 4) << 1)) = u;
            }
            #pragma unroll
            for (int i = 0; i < 2; ++i) {
                int tau = t + i * 256, kg = tau >> 7, n = tau & 127;
                int gc = n0 + n; if (gc > N - 1) gc = N - 1;
                const float* p = W + (size_t)(kk + kg * 8) * N + gc;
                uint4 u;
                u.x = bfpack(p[0], p[(size_t)N]);
                u.y = bfpack(p[2 * (size_t)N], p[3 * (size_t)N]);
                u.z = bfpack(p[4 * (size_t)N], p[5 * (size_t)N]);
                u.w = bfpack(p[6 * (size_t)N], p[7 * (size_t)N]);
                *(uint4*)((char*)lB + swzc(n, kg) * 16) = u;
            }
        }
        __syncthreads();

        const int kgl  = lane >> 4;
        const int lr16 = lane & 15;
        short8 af[4], bfr[4];
        #pragma unroll
        for (int mi = 0; mi < 4; ++mi) {
            const int row = wr * 64 + mi * 16 + lr16;
            af[mi] = *(const short8*)(lA + swzc(row, kgl) * 8);
        }
        #pragma unroll
        for (int ni = 0; ni < 4; ++ni) {
            const int row = wc * 64 + ni * 16 + lr16;
            bfr[ni] = *(const short8*)(lB + swzc(row, kgl) * 8);
        }
        #pragma unroll
        for (int mi = 0; mi < 4; ++mi)
            #pragma unroll
            for (int ni = 0; ni < 4; ++ni)
                acc[mi][ni] = __builtin_amdgcn_mfma_f32_16x16x32_bf16(
                    af[mi], bfr[ni], acc[mi][ni], 0, 0, 0);
        __syncthreads();
    }

    // ---- epilogue: bias add + closed-form scatter (verified R0)
    const int lr = lane & 15;
    const int lq = lane >> 4;
    #pragma unroll
    for (int ni = 0; ni < 4; ++ni) {
        const int n = n0 + wc * 64 + ni * 16 + lr;
        if (n >= N) continue;
        const float bias = BIAS[n];
        #pragma unroll
        for (int mi = 0; mi < 4; ++mi) {
            #pragma unroll
            for (int r = 0; r < 4; ++r) {
                const int m  = m0 + wr * 64 + mi * 16 + lq * 4 + r;
                const int b  = m >> LOGK;
                const int kd = m & (K_L - 1);
                const float v = acc[mi][ni][r] + bias;
                float* yb = Y + (size_t)b * 370816;
                if (MODE == 0) {
                    if (n < 27)       yb[kd * 27 + n] = v;
                    else if (n == 27) yb[1728 + kd]   = v;
                    else {
                        int tt = n - 28, kn = tt / 9, j = tt - kn * 9;
                        yb[1792 + kn * 576 + kd * 9 + j] = 0.5f * v;
                    }
                } else if (MODE == 1) {
                    if (n < 576)       yb[1792 + kd * 576 + n] += 0.5f * v;
                    else if (n == 576) yb[75520 + kd] = 0.5f * v;
                    else {
                        int tt = n - 577, kn = tt / 9, j = tt - kn * 9;
                        yb[75648 + kn * 1152 + kd * 9 + j] = v;
                    }
                } else {
                    if (n < 1152) yb[75648 + kd * 1152 + n] += v;
                    else          yb[370560 + kd] = v;
                }
            }
        }
    }
}

extern "C" void kernel_launch(void* const* d_in, const int* in_sizes, int n_in,
                              void* d_out, int out_size, void* d_ws, size_t ws_size,
                              hipStream_t stream)
{
    const float* x  = (const float*)d_in[0];
    const float* W0 = (const float*)d_in[1];
    const float* b0 = (const float*)d_in[2];
    const float* W1 = (const float*)d_in[3];
    const float* b1 = (const float*)d_in[4];
    const float* W2 = (const float*)d_in[5];
    const float* b2 = (const float*)d_in[6];
    float* y = (float*)d_out;

    // ws layout (bf16): XB[128*448*512] | WT0[1180*512] | WT1[2881*512] | WT2[1153*512]
    unsigned short* XB  = (unsigned short*)d_ws;
    unsigned short* WT0 = XB  + (size_t)128 * 448 * 512;
    unsigned short* WT1 = WT0 + (size_t)1180 * 512;
    unsigned short* WT2 = WT1 + (size_t)2881 * 512;
    const size_t NEED = ((size_t)128 * 448 * 512 + (size_t)(1180 + 2881 + 1153) * 512) * 2;

    if (ws_size >= NEED) {
        cvt_x<<<dim3(14336), 256, 0, stream>>>(x, XB);                       // 128*448*512/8/256
        cvt_w<1180><<<dim3((1180 * 64 + 255) / 256), 256, 0, stream>>>(W0, WT0);
        cvt_w<2881><<<dim3((2881 * 64 + 255) / 256), 256, 0, stream>>>(W1, WT1);
        cvt_w<1153><<<dim3((1153 * 64 + 255) / 256), 256, 0, stream>>>(W2, WT2);
        gemm_scatter<0, true><<<dim3(64 * 10),  256, 0, stream>>>(x, W0, XB, WT0, b0, y);
        gemm_scatter<1, true><<<dim3(128 * 23), 256, 0, stream>>>(x, W1, XB, WT1, b1, y);
        gemm_scatter<2, true><<<dim3(256 * 10), 256, 0, stream>>>(x, W2, XB, WT2, b2, y);
    } else {
        gemm_scatter<0, false><<<dim3(64 * 10),  256, 0, stream>>>(x, W0, XB, WT0, b0, y);
        gemm_scatter<1, false><<<dim3(128 * 23), 256, 0, stream>>>(x, W1, XB, WT1, b1, y);
        gemm_scatter<2, false><<<dim3(256 * 10), 256, 0, stream>>>(x, W2, XB, WT2, b2, y);
    }
}